// Round 12
// baseline (69.156 us; speedup 1.0000x reference)
//
#include <hip/hip_runtime.h>

// PS-RoI-Align (torchvision ps_roi_align semantics).
// feat: [4, 784, 112, 112] fp32; rois: [K,5]; out: [K, 16, 7, 7] fp32.
//
// R11: reg-staged plane streaming (T14 issue-early / write-late).
//   Scoreboard: ALL global_load_lds schedules pin at ~2.7us/plane/CU
//   (4.65 TB/s) -- depth-2 / counted-vmcnt / multi-block all neutral or
//   worse => suspected per-CU LDS-DMA fill-rate limit, not DRAM. R0's
//   to-register gathers hit 6.07 TB/s on this data; fillBuffer writes 7.
//   => stage via VGPRs: at TOP of round i, issue 7 global_load_dwordx4
//   per wave for plane i+2 (~1.7 rounds of flight); at END of round
//   (after compute) ds_write_b128 them into the LDS buffer. Barrier is
//   raw s_barrier + lgkmcnt(0) ONLY -- no vmcnt drain, so the in-flight
//   loads live across the barrier (R5's __syncthreads drained them).
//   Even/odd rounds unrolled so all stage-register indices are static.

#define PP 7
#define SR 2
#define SCALEF 0.0625f

constexpr int Cc     = 784;            // Cout * P * P
constexpr int Hh     = 112;
constexpr int Ww     = 112;
constexpr int PLANE  = Hh * Ww;        // 12544 floats = 50176 B
constexpr int CHUNKS = 49;             // 1KB chunks (64 lanes x 16 B)
constexpr int NBLK   = 256;            // 1 block / CU
constexpr int TPB    = 512;            // 8 waves
constexpr int RPT    = 2;              // rois per thread (K <= 1024)

// wave w owns chunks w, w+8, ... (wave0: 7 chunks, waves1-7: 6)
#define ISSUE7(rg, p) do {                                                  \
    const float4* s4_ = (const float4*)(feat + (size_t)(p) * PLANE);        \
    _Pragma("unroll")                                                       \
    for (int t_ = 0; t_ < 7; ++t_) {                                        \
        int j_ = wave + t_ * 8;                                             \
        if (j_ < CHUNKS) rg[t_] = s4_[j_ * 64 + lane];                      \
    } } while (0)

#define WRITE7(rg, dstv) do {                                               \
    _Pragma("unroll")                                                       \
    for (int t_ = 0; t_ < 7; ++t_) {                                        \
        int j_ = wave + t_ * 8;                                             \
        if (j_ < CHUNKS) (dstv)[j_ * 64 + lane] = rg[t_];                   \
    } } while (0)

__global__ __launch_bounds__(TPB) void psroi_persist_kernel(
    const float* __restrict__ feat,
    const float* __restrict__ rois,
    float* __restrict__ out,
    int K, int nplanes)
{
    __shared__ float4 bufv[2][PLANE / 4];   // 2 x 50176 B, 16B-aligned

    int tid  = threadIdx.x;
    int wave = tid >> 6;
    int lane = tid & 63;

    // ---- parse roi params once per block into registers ----
    int   rb[RPT];
    float x1[RPT], y1[RPT], bsh[RPT], bsw[RPT];
#pragma unroll
    for (int j = 0; j < RPT; ++j) {
        int k = tid + j * TPB;
        if (k < K) {
            const float* r = rois + (size_t)k * 5;
            rb[j]  = (int)r[0];
            x1[j]  = r[1] * SCALEF - 0.5f;
            y1[j]  = r[2] * SCALEF - 0.5f;
            float rw = fmaxf(r[3] * SCALEF - 0.5f - x1[j], 0.1f);
            float rh = fmaxf(r[4] * SCALEF - 0.5f - y1[j], 0.1f);
            bsh[j] = rh * (1.0f / (float)PP);
            bsw[j] = rw * (1.0f / (float)PP);
        } else {
            rb[j] = -1;
        }
    }

    // ---- compute one plane from LDS ----
    auto computeplane = [&](const float* pl, int p) {
        int b  = p / Cc;
        int c  = p % Cc;
        int pw = c % PP;
        int ph = (c % (PP * PP)) / PP;
#pragma unroll
        for (int j = 0; j < RPT; ++j) {
            if (rb[j] != b) continue;
            float acc = 0.0f;
#pragma unroll
            for (int iy = 0; iy < SR; ++iy) {
                float gy = ((float)iy + 0.5f) / (float)SR;
                float y  = y1[j] + ((float)ph + gy) * bsh[j];
                bool  vy = (y >= -1.0f) && (y <= (float)Hh);
                float yc = fminf(fmaxf(y, 0.0f), (float)(Hh - 1));
                int   yl = (int)yc;            // yc >= 0 -> trunc == floor
                int   yh = min(yl + 1, Hh - 1);
                float ly = yc - (float)yl;
                float hy = 1.0f - ly;
#pragma unroll
                for (int ix = 0; ix < SR; ++ix) {
                    float gx = ((float)ix + 0.5f) / (float)SR;
                    float x  = x1[j] + ((float)pw + gx) * bsw[j];
                    bool  vx = (x >= -1.0f) && (x <= (float)Ww);
                    float xc = fminf(fmaxf(x, 0.0f), (float)(Ww - 1));
                    int   xl = (int)xc;
                    int   xh = min(xl + 1, Ww - 1);
                    float lx = xc - (float)xl;
                    float hx = 1.0f - lx;

                    float v = hy * hx * pl[yl * Ww + xl]
                            + hy * lx * pl[yl * Ww + xh]
                            + ly * hx * pl[yh * Ww + xl]
                            + ly * lx * pl[yh * Ww + xh];
                    acc += (vy && vx) ? v : 0.0f;
                }
            }
            int k = tid + j * TPB;
            out[(size_t)k * Cc + c] = acc * (1.0f / (float)(SR * SR));
        }
    };

    // balanced contiguous partition: blocks 0..63 get 13 planes, rest 12
    int per   = nplanes / NBLK;
    int rem   = nplanes % NBLK;
    int bid   = blockIdx.x;
    int start = bid * per + min(bid, rem);
    int cnt   = per + (bid < rem ? 1 : 0);

    float4 ra[7], rz[7];

    // prologue: plane0 -> buf0; issue plane1 into rz
    ISSUE7(ra, start);
    if (cnt > 1) ISSUE7(rz, start + 1);
    WRITE7(ra, bufv[0]);                   // waits only ra's loads (older 7)
    asm volatile("s_waitcnt lgkmcnt(0)" ::: "memory");
    __builtin_amdgcn_s_barrier();

    int i = 0;
    while (true) {
        {   // even round: compute buf0; rz -> buf1; ra <- plane i+2
            int p = start + i;
            if (i + 2 < cnt) ISSUE7(ra, p + 2);
            computeplane((const float*)bufv[0], p);
            if (i + 1 < cnt) WRITE7(rz, bufv[1]);
            asm volatile("s_waitcnt lgkmcnt(0)" ::: "memory");
            __builtin_amdgcn_s_barrier();
            if (++i >= cnt) break;
        }
        {   // odd round: compute buf1; ra -> buf0; rz <- plane i+2
            int p = start + i;
            if (i + 2 < cnt) ISSUE7(rz, p + 2);
            computeplane((const float*)bufv[1], p);
            if (i + 1 < cnt) WRITE7(ra, bufv[0]);
            asm volatile("s_waitcnt lgkmcnt(0)" ::: "memory");
            __builtin_amdgcn_s_barrier();
            if (++i >= cnt) break;
        }
    }
}

extern "C" void kernel_launch(void* const* d_in, const int* in_sizes, int n_in,
                              void* d_out, int out_size, void* d_ws, size_t ws_size,
                              hipStream_t stream) {
    const float* feat = (const float*)d_in[0];
    const float* rois = (const float*)d_in[1];
    float* out = (float*)d_out;

    int K = in_sizes[1] / 5;
    int nplanes = in_sizes[0] / PLANE;          // N * Cc = 3136
    psroi_persist_kernel<<<NBLK, TPB, 0, stream>>>(feat, rois, out, K, nplanes);
}

// Round 13
// 37.687 us; speedup vs baseline: 1.8350x; 1.8350x over previous
//
#include <hip/hip_runtime.h>

// PS-RoI-Align (torchvision ps_roi_align semantics).
// feat: [4, 784, 112, 112] fp32; rois: [K,5]; out: [K, 16, 7, 7] fp32.
//
// R12 = R5 (best: 35.1us; stage-at-top depth-1 global_load_lds, double
// buffer, one __syncthreads per plane) + batch-sorted roi lists:
//   R5's compute phase ran every wave over every roi with ~25% lane
//   utilization (per-lane `if (batch!=b) continue`). Setup now buckets
//   rois by batch ONCE per block (two-pass LDS-atomic counting into SoA
//   param arrays; slot order is non-deterministic but outputs are
//   slot-independent -> deterministic). Per plane, only the ~K/4 matching
//   rois are processed, all 64 lanes active, uniform trip count (idle
//   waves exit on a uniform branch). Staging schedule identical to R5.

#define PP 7
#define SR 2
#define SCALEF 0.0625f

constexpr int Cc     = 784;            // Cout * P * P
constexpr int Hh     = 112;
constexpr int Ww     = 112;
constexpr int PLANE  = Hh * Ww;        // 12544 floats = 50176 B
constexpr int CHUNKS = 49;             // 1KB chunks (64 lanes x 16 B)
constexpr int NBLK   = 256;            // 1 block / CU
constexpr int TPB    = 512;            // 8 waves
constexpr int NB     = 4;              // batches
constexpr int KMAX   = 2048;           // roi capacity (K = 1024 here)

__global__ __launch_bounds__(TPB) void psroi_persist_kernel(
    const float* __restrict__ feat,
    const float* __restrict__ rois,
    float* __restrict__ out,
    int K, int nplanes)
{
    __shared__ float buf[2][PLANE];            // 100352 B
    __shared__ float px1[KMAX], py1[KMAX];     // 16 KB
    __shared__ float pbw[KMAX], pbh[KMAX];     // 16 KB
    __shared__ unsigned short pk[KMAX];        // 4 KB
    __shared__ int cnt[NB], off[NB], pos[NB];

    int tid  = threadIdx.x;
    int wave = tid >> 6;
    int lane = tid & 63;

    // ---- setup: bucket rois by batch into LDS SoA (once per block) ----
    if (tid < NB) cnt[tid] = 0;
    __syncthreads();
    for (int k = tid; k < K; k += TPB) {
        int b = (int)rois[(size_t)k * 5];
        atomicAdd(&cnt[b], 1);
    }
    __syncthreads();
    if (tid == 0) {
        int o = 0;
        for (int b = 0; b < NB; ++b) { off[b] = o; pos[b] = o; o += cnt[b]; }
    }
    __syncthreads();
    for (int k = tid; k < K; k += TPB) {
        const float* r = rois + (size_t)k * 5;
        int b = (int)r[0];
        int s = atomicAdd(&pos[b], 1);
        float x1 = r[1] * SCALEF - 0.5f;
        float y1 = r[2] * SCALEF - 0.5f;
        px1[s] = x1;
        py1[s] = y1;
        pbw[s] = fmaxf(r[3] * SCALEF - 0.5f - x1, 0.1f) * (1.0f / (float)PP);
        pbh[s] = fmaxf(r[4] * SCALEF - 0.5f - y1, 0.1f) * (1.0f / (float)PP);
        pk[s]  = (unsigned short)k;
    }
    // visibility of lists is covered by the prologue __syncthreads below

    // ---- async stage one plane into buf[bi]; wave w owns chunks w, w+8, ... ----
    auto stage = [&](int bi, int p) {
        const float* src = feat + (size_t)p * PLANE;
        for (int j = wave; j < CHUNKS; j += TPB / 64) {
            __builtin_amdgcn_global_load_lds(
                (const __attribute__((address_space(1))) void*)(src + j * 256 + lane * 4),
                (__attribute__((address_space(3))) void*)(&buf[bi][j * 256]),
                16, 0, 0);
        }
    };

    // balanced contiguous partition: blocks 0..63 get 13 planes, rest 12
    int per   = nplanes / NBLK;
    int rem   = nplanes % NBLK;
    int bid   = blockIdx.x;
    int start = bid * per + min(bid, rem);
    int cntp  = per + (bid < rem ? 1 : 0);

    stage(0, start);                       // prologue prefetch
    __syncthreads();                       // vmcnt(0) drain + barrier

    int cur = 0;
    for (int i = 0; i < cntp; ++i) {
        int p  = start + i;
        int pn = p + NBLK;                 // (unused: contiguous partition)
        (void)pn;
        if (i + 1 < cntp) stage(cur ^ 1, p + 1);   // prefetch next plane

        int b  = p / Cc;
        int c  = p % Cc;
        int pw = c % PP;
        int ph = (c % (PP * PP)) / PP;
        const float* pl = buf[cur];

        int base = off[b];
        int nb   = cnt[b];
        for (int t = tid; t < nb; t += TPB) {      // uniform trip count
            int   s  = base + t;
            float x1 = px1[s], y1 = py1[s];
            float bw = pbw[s], bh = pbh[s];

            float acc = 0.0f;
#pragma unroll
            for (int iy = 0; iy < SR; ++iy) {
                float gy = ((float)iy + 0.5f) / (float)SR;
                float y  = y1 + ((float)ph + gy) * bh;
                bool  vy = (y >= -1.0f) && (y <= (float)Hh);
                float yc = fminf(fmaxf(y, 0.0f), (float)(Hh - 1));
                int   yl = (int)yc;            // yc >= 0 -> trunc == floor
                int   yh = min(yl + 1, Hh - 1);
                float ly = yc - (float)yl;
                float hy = 1.0f - ly;
#pragma unroll
                for (int ix = 0; ix < SR; ++ix) {
                    float gx = ((float)ix + 0.5f) / (float)SR;
                    float x  = x1 + ((float)pw + gx) * bw;
                    bool  vx = (x >= -1.0f) && (x <= (float)Ww);
                    float xc = fminf(fmaxf(x, 0.0f), (float)(Ww - 1));
                    int   xl = (int)xc;
                    int   xh = min(xl + 1, Ww - 1);
                    float lx = xc - (float)xl;
                    float hx = 1.0f - lx;

                    float v = hy * hx * pl[yl * Ww + xl]
                            + hy * lx * pl[yl * Ww + xh]
                            + ly * hx * pl[yh * Ww + xl]
                            + ly * lx * pl[yh * Ww + xh];
                    acc += (vy && vx) ? v : 0.0f;
                }
            }
            out[(size_t)pk[s] * Cc + c] = acc * (1.0f / (float)(SR * SR));
        }

        __syncthreads();               // drain prefetch + protect cur before swap
        cur ^= 1;
    }
}

extern "C" void kernel_launch(void* const* d_in, const int* in_sizes, int n_in,
                              void* d_out, int out_size, void* d_ws, size_t ws_size,
                              hipStream_t stream) {
    const float* feat = (const float*)d_in[0];
    const float* rois = (const float*)d_in[1];
    float* out = (float*)d_out;

    int K = in_sizes[1] / 5;               // 1024 (KMAX = 2048 capacity)
    int nplanes = in_sizes[0] / PLANE;     // N * Cc = 3136
    psroi_persist_kernel<<<NBLK, TPB, 0, stream>>>(feat, rois, out, K, nplanes);
}